// Round 8
// baseline (202.991 us; speedup 1.0000x reference)
//
#include <hip/hip_runtime.h>

// RangeLoss, R8: decouple waves (no pre-compute __syncthreads).
// R7 post-mortem: the p_next exchange used LDS + __syncthreads between loads
// and compute, coupling every wave to the block's slowest load (miniature
// barrier-drain stall). This version: lanes 0..62 get p_next via intra-wave
// shfl; lane 63 issues a predicated 1-line global dword per chunk in the load
// phase. No barrier before compute — each wave runs as soon as ITS loads land.
// Fixed harness overhead in dur_us is ~145us (402MB poison fills + restores);
// controllable share ~55us vs ~35us floor.

#define N3      25165824                  // 8388608 * 3 floats
#define G4      6291456                   // N3 / 4 float4s
#define BLOCK   256
#define UNROLL  2
#define NB      (G4 / (BLOCK * UNROLL))   // 12288, exact
#define INV_TOTAL (1.0f / 25165824.0f)

typedef float vfloat4 __attribute__((ext_vector_type(4)));

__global__ void __launch_bounds__(BLOCK, 8) rangeloss_stage1(
    const vfloat4* __restrict__ preds4,
    const vfloat4* __restrict__ target4,
    const float*   __restrict__ predsf,
    float* __restrict__ partials)
{
    const int tid  = threadIdx.x;
    const int lane = tid & 63;
    const int wv   = tid >> 6;
    const int base = blockIdx.x * (BLOCK * UNROLL) + tid;

    // ---- load phase: 4 dwordx4 per thread + 1 predicated dword on lane 63 ----
    vfloat4 p[UNROLL], t[UNROLL];
    float   pn63[UNROLL];
    #pragma unroll
    for (int k = 0; k < UNROLL; ++k) {
        const int i = base + k * BLOCK;
        p[k] = preds4[i];
        t[k] = __builtin_nontemporal_load(&target4[i]);   // read-once stream
        // lane 63's p_next crosses the wave boundary: load it directly
        // (1 cache line per wave per chunk). Clamp guards the global-last
        // element, which is col 2 (value unused).
        if (lane == 63)
            pn63[k] = predsf[min(4 * i + 4, N3 - 1)];
    }
    __builtin_amdgcn_sched_barrier(0);   // keep all loads issued before compute

    // ---- p_next: intra-wave shfl, lane 63 from its own load. NO barrier. ----
    float pn[UNROLL];
    #pragma unroll
    for (int k = 0; k < UNROLL; ++k) {
        float nx = __shfl_down(p[k].x, 1, 64);   // lanes 0..62
        pn[k] = (lane == 63) ? pn63[k] : nx;
    }

    // ---- compute ----
    float sum = 0.0f;
    #pragma unroll
    for (int k = 0; k < UNROLL; ++k) {
        const int i  = base + k * BLOCK;
        const int ph = i % 3;     // col of element 0 is (4i)%3 = i%3

        const float pe[4]  = {p[k].x, p[k].y, p[k].z, p[k].w};
        const float te[4]  = {t[k].x, t[k].y, t[k].z, t[k].w};
        const float pnx[4] = {p[k].y, p[k].z, p[k].w, pn[k]};

        #pragma unroll
        for (int e = 0; e < 4; ++e) {
            int col = ph + e;
            col = (col >= 3) ? col - 3 : col;             // (ph+e) mod 3
            const bool is_c1 = (col == 1);

            const float pp = pe[e], tt = te[e];
            const float diff = pp - tt;

            // col 0/2: target is exactly 0.0 or 1.0 -> snap iff |p-t| < 0.1
            const bool r02 = __builtin_fabsf(diff) < 0.1f;
            // col 1: snap iff p_next>0.9 or p*1.02>t && p*0.98<t (exact ref form)
            const bool inr = (pp * 1.02f > tt) && (pp * 0.98f < tt);
            const bool r1  = (pnx[e] > 0.9f) || inr;

            const bool snap = is_c1 ? r1 : r02;
            const float d = snap ? 0.0f : diff;           // snapped => diff exactly 0
            sum = fmaf(d, d, sum);
        }
    }

    sum *= INV_TOTAL;  // pre-scale so summed partials equal the mean

    // wave-64 butterfly reduce
    #pragma unroll
    for (int off = 32; off > 0; off >>= 1)
        sum += __shfl_down(sum, off, 64);

    __shared__ float red[BLOCK / 64];
    if (lane == 0) red[wv] = sum;
    __syncthreads();

    if (tid == 0)
        partials[blockIdx.x] = red[0] + red[1] + red[2] + red[3];
}

#define S2BLOCK 1024

__global__ void __launch_bounds__(S2BLOCK) rangeloss_stage2(
    const float* __restrict__ partials,
    float* __restrict__ out)
{
    float sum = 0.0f;
    #pragma unroll
    for (int i = threadIdx.x; i < NB; i += S2BLOCK)
        sum += partials[i];

    #pragma unroll
    for (int off = 32; off > 0; off >>= 1)
        sum += __shfl_down(sum, off, 64);

    __shared__ float smem[S2BLOCK / 64];
    const int lane = threadIdx.x & 63;
    const int wave = threadIdx.x >> 6;
    if (lane == 0) smem[wave] = sum;
    __syncthreads();

    if (threadIdx.x == 0) {
        float s = 0.0f;
        #pragma unroll
        for (int w = 0; w < S2BLOCK / 64; ++w) s += smem[w];
        out[0] = s;  // overwrites poison
    }
}

extern "C" void kernel_launch(void* const* d_in, const int* in_sizes, int n_in,
                              void* d_out, int out_size, void* d_ws, size_t ws_size,
                              hipStream_t stream)
{
    const vfloat4* preds4  = (const vfloat4*)d_in[0];
    const vfloat4* target4 = (const vfloat4*)d_in[1];
    const float*   predsf  = (const float*)d_in[0];
    float* partials = (float*)d_ws;   // NB floats = 48 KB, fully written by stage 1
    float* out = (float*)d_out;

    rangeloss_stage1<<<NB, BLOCK, 0, stream>>>(preds4, target4, predsf, partials);
    rangeloss_stage2<<<1, S2BLOCK, 0, stream>>>(partials, out);
}